// Round 18
// baseline (225.391 us; speedup 1.0000x reference)
//
#include <hip/hip_runtime.h>
#include <math.h>

#define H 96
#define W 96
#define HW (H*W)
#define CIN 64
#define NB 4
#define NOFF 166
#define OFFROW 168   // padded offset row (166 used)
#define HWP (HW+1)   // xb row pitch: +1 zero guard pixel for OOB taps

typedef __attribute__((ext_vector_type(8)))  short short8;
typedef __attribute__((ext_vector_type(8)))  _Float16 half8;
typedef __attribute__((ext_vector_type(16))) float f32x16;
typedef unsigned short ushort_t;

// ---------------- ws layout (in float slots) ----------------
static const size_t OFF_ALL = 0;                                   // 4*HW*168 f32 (per-pos rows)
static const size_t RES     = OFF_ALL + (size_t)NB*HW*OFFROW;      // 4*192*HW f32
static const size_t XB16    = RES + (size_t)NB*192*HW;             // 4*(HW+1)*64 ushort (NHWC fp16 + guard)
static const size_t WTD3    = XB16 + (size_t)NB*64*HWP/2;          // 9*4096 ushort (fragment-major)
static const size_t WTD5    = WTD3 + 9*4096/2;                     // 25*4096 ushort
static const size_t WTD7    = WTD5 + 25*4096/2;                    // 49*4096 ushort
static const size_t WOFF    = WTD7 + 49*4096/2;                    // 9*192*64 ushort
static const size_t BOFF    = WOFF + 9*192*64/2;                   // 192 f32
static const size_t SPIN    = BOFF + 192;                          // 4*2*HW
static const size_t SPATT   = SPIN + (size_t)NB*2*HW;              // 4*HW
static const size_t POOLSUM = SPATT + (size_t)NB*HW;               // 768 f32 (atomic sums)
static const size_t POOLMAX = POOLSUM + NB*192;                    // 768 u32 (atomic max keys)
static const size_t CHATT   = POOLMAX + NB*192;                    // 768

// fp16 helpers
__device__ __forceinline__ ushort_t f2h(float f) {
    _Float16 h = (_Float16)f;
    return __builtin_bit_cast(unsigned short, h);
}
__device__ __forceinline__ half8 as_h8(short8 s) {
    return __builtin_bit_cast(half8, s);
}
__device__ __forceinline__ half8 splat8(float f) {
    _Float16 h = (_Float16)f;
    half8 v;
    #pragma unroll
    for (int j = 0; j < 8; j++) v[j] = h;
    return v;
}

// monotonic float <-> uint key (for atomicMax on floats incl. negatives)
__device__ __forceinline__ unsigned fenc(float f) {
    unsigned u = __float_as_uint(f);
    return (u & 0x80000000u) ? ~u : (u | 0x80000000u);
}
__device__ __forceinline__ float fdec(unsigned k) {
    return (k & 0x80000000u) ? __uint_as_float(k ^ 0x80000000u)
                             : __uint_as_float(~k);
}

// ---------------- prep: x->NHWC fp16, weight preprocessing, pool init -------
__global__ __launch_bounds__(256) void prep_kernel(
    const float* __restrict__ x, ushort_t* __restrict__ xb,
    const float* __restrict__ w3, const float* __restrict__ w5,
    const float* __restrict__ w7,
    const float* __restrict__ ob3, const float* __restrict__ ob5,
    const float* __restrict__ ob7,
    const float* __restrict__ ow3, const float* __restrict__ ow5,
    const float* __restrict__ ow7,
    ushort_t* __restrict__ wt3, ushort_t* __restrict__ wt5,
    ushort_t* __restrict__ wt7,
    ushort_t* __restrict__ woff, float* __restrict__ boff,
    float* __restrict__ sumb, unsigned* __restrict__ maxb)
{
    const int bid = blockIdx.x;
    const int t = threadIdx.x;
    if (bid == 2336) {                       // pool accumulator init
        for (int i = t; i < NB * 192; i += 256) {
            sumb[i] = 0.f;
            maxb[i] = 0u;                    // < any finite float's key
        }
        return;
    }
    if (bid < 576) {
        __shared__ ushort_t tile[64][66];
        int b = bid / 144;
        int p0 = (bid % 144) * 64;
        int q = t >> 6, ln = t & 63;
        #pragma unroll
        for (int i = 0; i < 16; i++) {
            int c = q * 16 + i;
            tile[ln][c] = f2h(x[((size_t)(b * 64 + c)) * HW + p0 + ln]);
        }
        if (p0 == 0 && t < 64) xb[((size_t)b * HWP + HW) * 64 + t] = 0;
        __syncthreads();
        #pragma unroll
        for (int i = 0; i < 16; i++) {
            int pos = q * 16 + i;
            xb[((size_t)b * HWP + p0 + pos) * 64 + ln] = tile[pos][ln];
        }
        return;
    }
    int idx = (bid - 576) * 256 + t;            // 83*4096 + 9*192*64 total
    if (idx < 83 * 4096) {
        const float* src; ushort_t* dst; int KK; int o;
        if (idx < 9 * 4096)       { src = w3; dst = wt3; KK = 9;  o = idx; }
        else if (idx < 34 * 4096) { src = w5; dst = wt5; KK = 25; o = idx - 9 * 4096; }
        else                      { src = w7; dst = wt7; KK = 49; o = idx - 34 * 4096; }
        int j    = o & 7;
        int l31  = (o >> 3) & 31;
        int lh   = (o >> 8) & 1;
        int cs   = (o >> 9) & 3;
        int half = (o >> 11) & 1;
        int kk   = o >> 12;
        int co = half * 32 + l31;
        int c  = cs * 16 + lh * 8 + j;
        dst[o] = f2h(src[((size_t)co * 64 + c) * KK + kk]);
        return;
    }
    int o = idx - 83 * 4096;                    // [0, 9*192*64)
    if (o >= 9 * 192 * 64) return;
    int c  = o & 63;
    int co = (o >> 6) % 192;
    int kk = o / (192 * 64);
    float v = 0.f;
    if (co < 18)       v = ow3[(co * 64 + c) * 9 + kk];
    else if (co < 68)  v = ow5[((co - 18) * 64 + c) * 9 + kk];
    else if (co < 166) v = ow7[((co - 68) * 64 + c) * 9 + kk];
    woff[(kk * 192 + co) * 64 + c] = f2h(v);
    if (kk == 0 && c == 0) {
        float bv = 0.f;
        if (co < 18)       bv = ob3[co];
        else if (co < 68)  bv = ob5[co - 18];
        else if (co < 166) bv = ob7[co - 68];
        boff[co] = bv;
    }
}

// ---------------- fused offset convs as MFMA implicit GEMM ------------------
__global__ __launch_bounds__(256, 3) void offset_mfma_kernel(
    const ushort_t* __restrict__ xb,        // NHWC fp16, pitch HWP
    const ushort_t* __restrict__ woff,      // [9][192][64] fp16
    const float* __restrict__ bias_all,     // [192]
    float* __restrict__ off_all)
{
    __shared__ float red[6144];
    const int t = threadIdx.x;
    const int lane = t & 63, l31 = lane & 31, lh = lane >> 5;
    const int wave = t >> 6;
    const int mhalf = wave >> 1, khalf = wave & 1;
    const int xcd = blockIdx.x & 7, u = blockIdx.x >> 3;
    const int b = xcd >> 1;
    const int v = u * 2 + (xcd & 1);        // [0,288)
    const int npos = v * 32 + l31;
    const int h = npos / 96, w = npos % 96;
    const int c0 = 8 * lh;
    const ushort_t* xbase = xb + (size_t)b * HWP * 64;

    f32x16 acc0, acc1, acc2;
    #pragma unroll
    for (int r = 0; r < 16; r++) { acc0[r] = 0.f; acc1[r] = 0.f; acc2[r] = 0.f; }

    const int kk0 = khalf ? 5 : 0, kk1 = khalf ? 9 : 5;
    const int mt0 = mhalf * 3;
    for (int kk = kk0; kk < kk1; kk++) {
        int ky = kk / 3, kx = kk % 3;
        int y = h + ky - 1, x = w + kx - 1;
        bool ok = ((unsigned)y < (unsigned)H) && ((unsigned)x < (unsigned)W);
        int o = ok ? (y * W + x) : HW;      // guard pixel = zeros
        const ushort_t* px = xbase + (size_t)o * 64 + c0;
        const ushort_t* wk = woff + (size_t)kk * 12288;
        #pragma unroll
        for (int cs = 0; cs < 4; cs++) {
            int cc = cs * 16;
            half8 bfrag = as_h8(*(const short8*)(px + cc));
            half8 a0 = as_h8(*(const short8*)(wk + (size_t)((mt0 + 0) * 32 + l31) * 64 + cc + c0));
            half8 a1 = as_h8(*(const short8*)(wk + (size_t)((mt0 + 1) * 32 + l31) * 64 + cc + c0));
            half8 a2 = as_h8(*(const short8*)(wk + (size_t)((mt0 + 2) * 32 + l31) * 64 + cc + c0));
            acc0 = __builtin_amdgcn_mfma_f32_32x32x16_f16(a0, bfrag, acc0, 0, 0, 0);
            acc1 = __builtin_amdgcn_mfma_f32_32x32x16_f16(a1, bfrag, acc1, 0, 0, 0);
            acc2 = __builtin_amdgcn_mfma_f32_32x32x16_f16(a2, bfrag, acc2, 0, 0, 0);
        }
    }

    if (khalf) {
        float* rp = red + mhalf * 3072;
        #pragma unroll
        for (int r = 0; r < 16; r++) {
            rp[(0 * 16 + r) * 64 + lane] = acc0[r];
            rp[(1 * 16 + r) * 64 + lane] = acc1[r];
            rp[(2 * 16 + r) * 64 + lane] = acc2[r];
        }
    }
    __syncthreads();
    if (!khalf) {
        const float* rp = red + mhalf * 3072;
        #pragma unroll
        for (int r = 0; r < 16; r++) {
            acc0[r] += rp[(0 * 16 + r) * 64 + lane];
            acc1[r] += rp[(1 * 16 + r) * 64 + lane];
            acc2[r] += rp[(2 * 16 + r) * 64 + lane];
        }
        float* row = off_all + ((size_t)b * HW + npos) * OFFROW;
        #pragma unroll
        for (int m = 0; m < 3; m++) {
            const f32x16& a = (m == 0) ? acc0 : (m == 1) ? acc1 : acc2;
            int mt = mt0 + m;
            #pragma unroll
            for (int q = 0; q < 4; q++) {
                int base = mt * 32 + 8 * q + 4 * lh;
                if (base < 166) {
                    float4 vv = make_float4(a[4 * q + 0] + bias_all[base + 0],
                                            a[4 * q + 1] + bias_all[base + 1],
                                            a[4 * q + 2] + bias_all[base + 2],
                                            a[4 * q + 3] + bias_all[base + 3]);
                    *(float4*)(row + base) = vv;
                }
            }
        }
    }
}

// store + accumulate per-position (sum,max) for spin AND per-channel
// (sum,max) for the global pool (32-lane shfl reduce + atomics).
__device__ __forceinline__ void store_tile_stats(int b, int tile, int lane, int g,
                                                 const float* __restrict__ bias,
                                                 const f32x16& acc0, const f32x16& acc1,
                                                 float* __restrict__ res,
                                                 float& psum, float& pmax,
                                                 float* __restrict__ sumb,
                                                 unsigned* __restrict__ maxb)
{
    const int l31 = lane & 31, lh = lane >> 5;
    const int npos = tile * 32 + l31;
    size_t rb = (((size_t)b * 3 + g) * 64) * HW + npos;
    #pragma unroll
    for (int r = 0; r < 16; r++) {
        int co = (r & 3) + 8 * (r >> 2) + 4 * lh;
        float v0 = acc0[r] + bias[co];
        float v1 = acc1[r] + bias[co + 32];
        res[rb + (size_t)co * HW]        = v0;
        res[rb + (size_t)(co + 32) * HW] = v1;
        psum += v0 + v1;
        pmax = fmaxf(pmax, fmaxf(v0, v1));
        // per-channel reduce over the 32 positions (half-wave)
        float s0 = v0, s1 = v1, m0 = v0, m1 = v1;
        #pragma unroll
        for (int d = 1; d < 32; d <<= 1) {
            s0 += __shfl_xor(s0, d);
            s1 += __shfl_xor(s1, d);
            m0 = fmaxf(m0, __shfl_xor(m0, d));
            m1 = fmaxf(m1, __shfl_xor(m1, d));
        }
        if (l31 == co) {
            atomicAdd(&sumb[co], s0);
            atomicAdd(&sumb[co + 32], s1);
            atomicMax(&maxb[co], fenc(m0));
            atomicMax(&maxb[co + 32], fenc(m1));
        }
    }
}

// patch geometry (K7-sized, shared by all three convs) -- R6 proven config
#define MG  5
#define PNY 12
#define PNX 43
#define PXS 144             // px stride bytes (128B data + 16B pad)
#define PRS (PNX * PXS)

// ---------------- one tap span from the staged LDS patch --------------------
template<int K, int PAD>
__device__ __forceinline__ void deform_span(
    const float* __restrict__ offp, const ushort_t* __restrict__ wtf,
    int kk0, int kk1, int h, int w, int w0, int l31, int lh,
    const char* lds, f32x16& acc0, f32x16& acc1)
{
    const int lh16 = lh * 16;
    const float2* offp2 = (const float2*)offp;
    float2 off = offp2[kk0];
    for (int kk = kk0; kk < kk1; kk++) {
        float2 noff = offp2[(kk + 1 < kk1) ? kk + 1 : kk];

        int ky = kk / K, kx = kk % K;
        float ys = (float)(h + ky - PAD) + off.x;
        float xs = (float)(w + kx - PAD) + off.y;
        float y0f = floorf(ys), x0f = floorf(xs);
        float fy = ys - y0f, fx = xs - x0f;
        int iy0 = (int)y0f, ix0 = (int)x0f;
        int iy1 = iy0 + 1, ix1 = ix0 + 1;
        float oky0 = ((unsigned)iy0 < (unsigned)H) ? 1.f : 0.f;
        float oky1 = ((unsigned)iy1 < (unsigned)H) ? 1.f : 0.f;
        float okx0 = ((unsigned)ix0 < (unsigned)W) ? 1.f : 0.f;
        float okx1 = ((unsigned)ix1 < (unsigned)W) ? 1.f : 0.f;
        float w00 = (1.f - fy) * (1.f - fx) * oky0 * okx0;
        float w01 = (1.f - fy) * fx * oky0 * okx1;
        float w10 = fy * (1.f - fx) * oky1 * okx0;
        float w11 = fy * fx * oky1 * okx1;
        int cy0 = min(max(iy0, 0), H - 1), cy1 = min(max(iy1, 0), H - 1);
        int cx0 = min(max(ix0, 0), W - 1), cx1 = min(max(ix1, 0), W - 1);
        int r0 = min(max(cy0 - h + MG, 0), PNY - 1);
        int r1 = min(max(cy1 - h + MG, 0), PNY - 1);
        int p0 = min(max(cx0 - w0 + MG, 0), PNX - 1);
        int p1 = min(max(cx1 - w0 + MG, 0), PNX - 1);
        const char* b00 = lds + r0 * PRS + p0 * PXS + lh16;
        const char* b01 = lds + r0 * PRS + p1 * PXS + lh16;
        const char* b10 = lds + r1 * PRS + p0 * PXS + lh16;
        const char* b11 = lds + r1 * PRS + p1 * PXS + lh16;

        half8 W00 = splat8(w00), W01 = splat8(w01);
        half8 W10 = splat8(w10), W11 = splat8(w11);
        const ushort_t* wkf = wtf + (size_t)kk * 4096;
        #pragma unroll
        for (int cs = 0; cs < 4; cs++) {
            half8 q00 = *(const half8*)(b00 + cs * 32);
            half8 q01 = *(const half8*)(b01 + cs * 32);
            half8 q10 = *(const half8*)(b10 + cs * 32);
            half8 q11 = *(const half8*)(b11 + cs * 32);
            half8 bfrag = q00 * W00 + q01 * W01 + q10 * W10 + q11 * W11;
            half8 a0 = as_h8(*(const short8*)(wkf + (size_t)(((0 * 4 + cs) * 2 + lh) * 32 + l31) * 8));
            half8 a1 = as_h8(*(const short8*)(wkf + (size_t)(((1 * 4 + cs) * 2 + lh) * 32 + l31) * 8));
            acc0 = __builtin_amdgcn_mfma_f32_32x32x16_f16(a0, bfrag, acc0, 0, 0, 0);
            acc1 = __builtin_amdgcn_mfma_f32_32x32x16_f16(a1, bfrag, acc1, 0, 0, 0);
        }
        off = noff;
    }
}

// ---------------- fully-fused deformable conv + spin + pool epilogues -------
__global__ __launch_bounds__(256, 2) void deform_fused_kernel(
    const ushort_t* __restrict__ xb, const float* __restrict__ off_all,
    const ushort_t* __restrict__ wt3, const ushort_t* __restrict__ wt5,
    const ushort_t* __restrict__ wt7,
    const float* __restrict__ b3, const float* __restrict__ b5,
    const float* __restrict__ b7,
    float* __restrict__ res, float* __restrict__ spin,
    float* __restrict__ sumb, unsigned* __restrict__ maxb)
{
    __shared__ __align__(16) char lds[PNY * PNX * PXS];   // 74304B
    const int t = threadIdx.x;
    const int wave = t >> 6, lane = t & 63;
    const int xcd = blockIdx.x & 7, u = blockIdx.x >> 3;
    const int b = xcd >> 1;
    const int tile = u * 2 + (xcd & 1);     // [0,288)

    const int l31 = lane & 31, lh = lane >> 5;
    const int h  = tile / 3;
    const int w0 = (tile % 3) * 32;
    const int w  = w0 + l31;
    const int npos = h * 96 + w;

    // ---- cooperative staging: PNY x PNX px, 8 x 16B chunks each ----
    const ushort_t* xsrc = xb + (size_t)b * HWP * 64;
    constexpr int NCH = PNY * PNX * 8;
    constexpr int NITER = (NCH + 255) / 256;
    #pragma unroll
    for (int it = 0; it < NITER; it++) {
        int c = t + it * 256;
        if (c < NCH) {
            int rr  = c / (PNX * 8);
            int rem = c - rr * (PNX * 8);
            int pp  = rem >> 3, sub = rem & 7;
            int cy = min(max(h - MG + rr, 0), H - 1);
            int cx = min(max(w0 - MG + pp, 0), W - 1);
            *(float4*)(lds + rr * PRS + pp * PXS + sub * 16) =
                *(const float4*)(xsrc + ((size_t)(cy * W + cx)) * 64 + sub * 8);
        }
    }
    __syncthreads();

    const float* offrow = off_all + ((size_t)b * HW + npos) * OFFROW;

    f32x16 a0A, a1A, a0B, a1B;
    #pragma unroll
    for (int r = 0; r < 16; r++) { a0A[r] = 0.f; a1A[r] = 0.f; a0B[r] = 0.f; a1B[r] = 0.f; }

    if (wave == 0) {
        deform_span<3, 1>(offrow + 0,  wt3, 0, 9,  h, w, w0, l31, lh, lds, a0A, a1A);
        deform_span<5, 2>(offrow + 18, wt5, 0, 12, h, w, w0, l31, lh, lds, a0B, a1B);
    } else if (wave == 1) {
        deform_span<5, 2>(offrow + 18, wt5, 12, 25, h, w, w0, l31, lh, lds, a0A, a1A);
        deform_span<7, 3>(offrow + 68, wt7, 0, 8,   h, w, w0, l31, lh, lds, a0B, a1B);
    } else if (wave == 2) {
        deform_span<7, 3>(offrow + 68, wt7, 8, 29,  h, w, w0, l31, lh, lds, a0A, a1A);
    } else {
        deform_span<7, 3>(offrow + 68, wt7, 29, 49, h, w, w0, l31, lh, lds, a0A, a1A);
    }

    // ---- cross-wave reduce in the (dead) patch area ----
    __syncthreads();
    float* slots = (float*)lds;
    if (wave == 1) {
        float* s0 = slots;            // w1.A  (K5 partial)
        float* s1 = slots + 2048;     // w1.B  (K7 partial)
        #pragma unroll
        for (int r = 0; r < 16; r++) {
            s0[r * 64 + lane]        = a0A[r];
            s0[(16 + r) * 64 + lane] = a1A[r];
            s1[r * 64 + lane]        = a0B[r];
            s1[(16 + r) * 64 + lane] = a1B[r];
        }
    } else if (wave == 3) {
        float* s2 = slots + 4096;     // w3.A  (K7 partial)
        #pragma unroll
        for (int r = 0; r < 16; r++) {
            s2[r * 64 + lane]        = a0A[r];
            s2[(16 + r) * 64 + lane] = a1A[r];
        }
    }
    __syncthreads();
    float psum = 0.f, pmax = -3.402823466e+38f;
    if (wave == 0) {
        store_tile_stats(b, tile, lane, 0, b3, a0A, a1A, res, psum, pmax,
                         sumb + b * 192 + 0, maxb + b * 192 + 0);
        const float* s0 = slots;
        #pragma unroll
        for (int r = 0; r < 16; r++) {
            a0B[r] += s0[r * 64 + lane];
            a1B[r] += s0[(16 + r) * 64 + lane];
        }
        store_tile_stats(b, tile, lane, 1, b5, a0B, a1B, res, psum, pmax,
                         sumb + b * 192 + 64, maxb + b * 192 + 64);
    } else if (wave == 2) {
        const float* s1 = slots + 2048;
        const float* s2 = slots + 4096;
        #pragma unroll
        for (int r = 0; r < 16; r++) {
            a0A[r] += s1[r * 64 + lane] + s2[r * 64 + lane];
            a1A[r] += s1[(16 + r) * 64 + lane] + s2[(16 + r) * 64 + lane];
        }
        store_tile_stats(b, tile, lane, 2, b7, a0A, a1A, res, psum, pmax,
                         sumb + b * 192 + 128, maxb + b * 192 + 128);
    }
    // combine lh halves; stage per-position partials in dead LDS (byte 32768+)
    if (wave == 0 || wave == 2) {
        psum += __shfl_xor(psum, 32);
        pmax = fmaxf(pmax, __shfl_xor(pmax, 32));
        if (lane < 32) {
            float* pr = (float*)lds + 8192 + (wave == 2 ? 64 : 0);
            pr[lane * 2]     = psum;
            pr[lane * 2 + 1] = pmax;
        }
    }
    __syncthreads();
    if (wave == 1 && lane < 32) {
        const float* pr = (const float*)lds + 8192;
        float s = pr[lane * 2]     + pr[64 + lane * 2];
        float m = fmaxf(pr[lane * 2 + 1], pr[64 + lane * 2 + 1]);
        int np = tile * 32 + lane;
        spin[(size_t)b * 2 * HW + np]      = s * (1.f / 192.f);
        spin[(size_t)b * 2 * HW + HW + np] = m;
    }
}

// ---------------- attention maps: 7x7 spatial conv AND channel MLP ----------
__global__ __launch_bounds__(256) void att_kernel(
    const float* __restrict__ spin, const float* __restrict__ w_sp,
    float* __restrict__ sp,
    const float* __restrict__ sumb, const unsigned* __restrict__ maxb,
    const float* __restrict__ w1, const float* __restrict__ w2,
    float* __restrict__ ch)
{
    const int bid = blockIdx.x;
    const int t = threadIdx.x;
    if (bid < 576) {
        int gt  = bid * 256 + t;
        int idx = gt >> 2;
        int q   = gt & 3;
        int w = idx % W;
        int h = (idx / W) % H;
        int b = idx / HW;
        int ci  = q >> 1;
        int dy0 = (q & 1) ? 4 : 0;
        int dy1 = (q & 1) ? 7 : 4;
        const float* pin = spin + ((size_t)b * 2 + ci) * HW;
        const float* wp  = w_sp + ci * 49;
        float acc = 0.f;
        for (int dy = dy0; dy < dy1; dy++) {
            int yy = h + dy - 3;
            if (yy < 0 || yy >= H) continue;
            #pragma unroll
            for (int dx = 0; dx < 7; dx++) {
                int xx = w + dx - 3;
                if (xx < 0 || xx >= W) continue;
                acc = fmaf(pin[yy * W + xx], wp[dy * 7 + dx], acc);
            }
        }
        acc += __shfl_xor(acc, 1);
        acc += __shfl_xor(acc, 2);
        if (q == 0) sp[idx] = 1.f / (1.f + expf(-acc));
        return;
    }
    int b = bid - 576;
    __shared__ float sa[192], sm_[192], h1a[12], h1m[12];
    if (t < 192) {
        sa[t]  = sumb[b * 192 + t] * (1.f / (float)HW);
        sm_[t] = fdec(maxb[b * 192 + t]);
    }
    __syncthreads();
    if (t < 192) {
        int j = t >> 4, lg = t & 15;
        float s1 = 0.f, s2 = 0.f;
        #pragma unroll
        for (int i = 0; i < 12; i++) {
            int c = lg + i * 16;
            float wv = w1[j * 192 + c];
            s1 = fmaf(wv, sa[c], s1);
            s2 = fmaf(wv, sm_[c], s2);
        }
        #pragma unroll
        for (int d = 1; d < 16; d <<= 1) {
            s1 += __shfl_xor(s1, d);
            s2 += __shfl_xor(s2, d);
        }
        if (lg == 0) {
            h1a[j] = fmaxf(s1, 0.f);
            h1m[j] = fmaxf(s2, 0.f);
        }
    }
    __syncthreads();
    if (t < 192) {
        float s = 0.f;
        #pragma unroll
        for (int j = 0; j < 12; j++)
            s = fmaf(w2[t * 12 + j], h1a[j] + h1m[j], s);
        ch[b * 192 + t] = 1.f / (1.f + expf(-s));
    }
}

// ---------------- final combine (float4, 4 hw per thread) -------------------
__global__ void final_kernel(const float* __restrict__ res,
                             const float* __restrict__ sp,
                             const float* __restrict__ ch,
                             float* __restrict__ out) {
    int idx = blockIdx.x * 256 + threadIdx.x;   // NB*64*(HW/4)
    int hw4 = idx % (HW / 4);
    int co  = (idx / (HW / 4)) % 64;
    int b   = idx / (64 * (HW / 4));
    size_t rb = (size_t)b * 192 * HW + (size_t)co * HW + hw4 * 4;
    float4 a1 = *(const float4*)(res + rb);
    float4 a2 = *(const float4*)(res + rb + (size_t)64 * HW);
    float4 a3 = *(const float4*)(res + rb + (size_t)128 * HW);
    float4 spv = *(const float4*)(sp + (size_t)b * HW + hw4 * 4);
    float c1 = ch[b * 192 + co];
    float c2 = ch[b * 192 + 64 + co];
    float c3 = ch[b * 192 + 128 + co];
    float4 o;
    o.x = a1.x * (spv.x + c1) + a2.x * (spv.x + c2) + a3.x * (spv.x + c3);
    o.y = a1.y * (spv.y + c1) + a2.y * (spv.y + c2) + a3.y * (spv.y + c3);
    o.z = a1.z * (spv.z + c1) + a2.z * (spv.z + c2) + a3.z * (spv.z + c3);
    o.w = a1.w * (spv.w + c1) + a2.w * (spv.w + c2) + a3.w * (spv.w + c3);
    *(float4*)(out + ((size_t)b * 64 + co) * HW + hw4 * 4) = o;
}

extern "C" void kernel_launch(void* const* d_in, const int* in_sizes, int n_in,
                              void* d_out, int out_size, void* d_ws, size_t ws_size,
                              hipStream_t stream) {
    const float* x      = (const float*)d_in[0];
    const float* w_off3 = (const float*)d_in[1];
    const float* b_off3 = (const float*)d_in[2];
    const float* w_off5 = (const float*)d_in[3];
    const float* b_off5 = (const float*)d_in[4];
    const float* w_off7 = (const float*)d_in[5];
    const float* b_off7 = (const float*)d_in[6];
    const float* w_d3   = (const float*)d_in[7];
    const float* b_d3   = (const float*)d_in[8];
    const float* w_d5   = (const float*)d_in[9];
    const float* b_d5   = (const float*)d_in[10];
    const float* w_d7   = (const float*)d_in[11];
    const float* b_d7   = (const float*)d_in[12];
    const float* w_sp   = (const float*)d_in[13];
    const float* w_ca1  = (const float*)d_in[14];
    const float* w_ca2  = (const float*)d_in[15];

    float* ws = (float*)d_ws;
    float* off_all = ws + OFF_ALL;
    float* res     = ws + RES;
    ushort_t* xb16 = (ushort_t*)(ws + XB16);
    ushort_t* wt3  = (ushort_t*)(ws + WTD3);
    ushort_t* wt5  = (ushort_t*)(ws + WTD5);
    ushort_t* wt7  = (ushort_t*)(ws + WTD7);
    ushort_t* woff = (ushort_t*)(ws + WOFF);
    float* boff = ws + BOFF;
    float* spin = ws + SPIN;
    float* sp   = ws + SPATT;
    float* sumb = ws + POOLSUM;
    unsigned* maxb = (unsigned*)(ws + POOLMAX);
    float* chp  = ws + CHATT;

    prep_kernel<<<2337, 256, 0, stream>>>(x, xb16, w_d3, w_d5, w_d7,
                                          b_off3, b_off5, b_off7,
                                          w_off3, w_off5, w_off7,
                                          wt3, wt5, wt7, woff, boff,
                                          sumb, maxb);

    offset_mfma_kernel<<<1152, 256, 0, stream>>>(xb16, woff, boff, off_all);

    deform_fused_kernel<<<1152, 256, 0, stream>>>(xb16, off_all, wt3, wt5, wt7,
                                                  b_d3, b_d5, b_d7, res, spin,
                                                  sumb, maxb);

    att_kernel<<<580, 256, 0, stream>>>(spin, w_sp, sp, sumb, maxb,
                                        w_ca1, w_ca2, chp);

    final_kernel<<<2304, 256, 0, stream>>>(res, sp, chp, (float*)d_out);
}

// Round 19
// 146.109 us; speedup vs baseline: 1.5426x; 1.5426x over previous
//
#include <hip/hip_runtime.h>
#include <math.h>

#define H 96
#define W 96
#define HW (H*W)
#define CIN 64
#define NB 4
#define NOFF 166
#define OFFROW 168   // padded offset row (166 used)
#define HWP (HW+1)   // xb row pitch: +1 zero guard pixel for OOB taps

typedef __attribute__((ext_vector_type(8)))  short short8;
typedef __attribute__((ext_vector_type(8)))  _Float16 half8;
typedef __attribute__((ext_vector_type(16))) float f32x16;
typedef unsigned short ushort_t;

// ---------------- ws layout (in float slots) ----------------
static const size_t OFF_ALL = 0;                                   // 4*HW*168 f32 (per-pos rows)
static const size_t RES     = OFF_ALL + (size_t)NB*HW*OFFROW;      // 4*192*HW f32
static const size_t XB16    = RES + (size_t)NB*192*HW;             // 4*(HW+1)*64 ushort (NHWC fp16 + guard)
static const size_t WTD3    = XB16 + (size_t)NB*64*HWP/2;          // 9*4096 ushort (fragment-major)
static const size_t WTD5    = WTD3 + 9*4096/2;                     // 25*4096 ushort
static const size_t WTD7    = WTD5 + 25*4096/2;                    // 49*4096 ushort
static const size_t WOFF    = WTD7 + 49*4096/2;                    // 9*192*64 ushort
static const size_t BOFF    = WOFF + 9*192*64/2;                   // 192 f32
static const size_t SPIN    = BOFF + 192;                          // 4*2*HW
static const size_t SPATT   = SPIN + (size_t)NB*2*HW;              // 4*HW
static const size_t POOLAVG = SPATT + (size_t)NB*HW;               // 768
static const size_t POOLMAX = POOLAVG + NB*192;                    // 768
static const size_t CHATT   = POOLMAX + NB*192;                    // 768

// fp16 helpers
__device__ __forceinline__ ushort_t f2h(float f) {
    _Float16 h = (_Float16)f;
    return __builtin_bit_cast(unsigned short, h);
}
__device__ __forceinline__ half8 as_h8(short8 s) {
    return __builtin_bit_cast(half8, s);
}
__device__ __forceinline__ half8 splat8(float f) {
    _Float16 h = (_Float16)f;
    half8 v;
    #pragma unroll
    for (int j = 0; j < 8; j++) v[j] = h;
    return v;
}

// ---------------- prep: x->NHWC fp16 AND all weight preprocessing -----------
__global__ __launch_bounds__(256) void prep_kernel(
    const float* __restrict__ x, ushort_t* __restrict__ xb,
    const float* __restrict__ w3, const float* __restrict__ w5,
    const float* __restrict__ w7,
    const float* __restrict__ ob3, const float* __restrict__ ob5,
    const float* __restrict__ ob7,
    const float* __restrict__ ow3, const float* __restrict__ ow5,
    const float* __restrict__ ow7,
    ushort_t* __restrict__ wt3, ushort_t* __restrict__ wt5,
    ushort_t* __restrict__ wt7,
    ushort_t* __restrict__ woff, float* __restrict__ boff)
{
    const int bid = blockIdx.x;
    const int t = threadIdx.x;
    if (bid < 576) {
        __shared__ ushort_t tile[64][66];
        int b = bid / 144;
        int p0 = (bid % 144) * 64;
        int q = t >> 6, ln = t & 63;
        #pragma unroll
        for (int i = 0; i < 16; i++) {
            int c = q * 16 + i;
            tile[ln][c] = f2h(x[((size_t)(b * 64 + c)) * HW + p0 + ln]);
        }
        if (p0 == 0 && t < 64) xb[((size_t)b * HWP + HW) * 64 + t] = 0;
        __syncthreads();
        #pragma unroll
        for (int i = 0; i < 16; i++) {
            int pos = q * 16 + i;
            xb[((size_t)b * HWP + p0 + pos) * 64 + ln] = tile[pos][ln];
        }
        return;
    }
    int idx = (bid - 576) * 256 + t;            // 83*4096 + 9*192*64 total
    if (idx < 83 * 4096) {
        const float* src; ushort_t* dst; int KK; int o;
        if (idx < 9 * 4096)       { src = w3; dst = wt3; KK = 9;  o = idx; }
        else if (idx < 34 * 4096) { src = w5; dst = wt5; KK = 25; o = idx - 9 * 4096; }
        else                      { src = w7; dst = wt7; KK = 49; o = idx - 34 * 4096; }
        int j    = o & 7;
        int l31  = (o >> 3) & 31;
        int lh   = (o >> 8) & 1;
        int cs   = (o >> 9) & 3;
        int half = (o >> 11) & 1;
        int kk   = o >> 12;
        int co = half * 32 + l31;
        int c  = cs * 16 + lh * 8 + j;
        dst[o] = f2h(src[((size_t)co * 64 + c) * KK + kk]);
        return;
    }
    int o = idx - 83 * 4096;                    // [0, 9*192*64)
    if (o >= 9 * 192 * 64) return;
    int c  = o & 63;
    int co = (o >> 6) % 192;
    int kk = o / (192 * 64);
    float v = 0.f;
    if (co < 18)       v = ow3[(co * 64 + c) * 9 + kk];
    else if (co < 68)  v = ow5[((co - 18) * 64 + c) * 9 + kk];
    else if (co < 166) v = ow7[((co - 68) * 64 + c) * 9 + kk];
    woff[(kk * 192 + co) * 64 + c] = f2h(v);
    if (kk == 0 && c == 0) {
        float bv = 0.f;
        if (co < 18)       bv = ob3[co];
        else if (co < 68)  bv = ob5[co - 18];
        else if (co < 166) bv = ob7[co - 68];
        boff[co] = bv;
    }
}

// ---------------- fused offset convs as MFMA implicit GEMM ------------------
__global__ __launch_bounds__(256, 3) void offset_mfma_kernel(
    const ushort_t* __restrict__ xb,        // NHWC fp16, pitch HWP
    const ushort_t* __restrict__ woff,      // [9][192][64] fp16
    const float* __restrict__ bias_all,     // [192]
    float* __restrict__ off_all)
{
    __shared__ float red[6144];
    const int t = threadIdx.x;
    const int lane = t & 63, l31 = lane & 31, lh = lane >> 5;
    const int wave = t >> 6;
    const int mhalf = wave >> 1, khalf = wave & 1;
    const int xcd = blockIdx.x & 7, u = blockIdx.x >> 3;
    const int b = xcd >> 1;
    const int v = u * 2 + (xcd & 1);        // [0,288)
    const int npos = v * 32 + l31;
    const int h = npos / 96, w = npos % 96;
    const int c0 = 8 * lh;
    const ushort_t* xbase = xb + (size_t)b * HWP * 64;

    f32x16 acc0, acc1, acc2;
    #pragma unroll
    for (int r = 0; r < 16; r++) { acc0[r] = 0.f; acc1[r] = 0.f; acc2[r] = 0.f; }

    const int kk0 = khalf ? 5 : 0, kk1 = khalf ? 9 : 5;
    const int mt0 = mhalf * 3;
    for (int kk = kk0; kk < kk1; kk++) {
        int ky = kk / 3, kx = kk % 3;
        int y = h + ky - 1, x = w + kx - 1;
        bool ok = ((unsigned)y < (unsigned)H) && ((unsigned)x < (unsigned)W);
        int o = ok ? (y * W + x) : HW;      // guard pixel = zeros
        const ushort_t* px = xbase + (size_t)o * 64 + c0;
        const ushort_t* wk = woff + (size_t)kk * 12288;
        #pragma unroll
        for (int cs = 0; cs < 4; cs++) {
            int cc = cs * 16;
            half8 bfrag = as_h8(*(const short8*)(px + cc));
            half8 a0 = as_h8(*(const short8*)(wk + (size_t)((mt0 + 0) * 32 + l31) * 64 + cc + c0));
            half8 a1 = as_h8(*(const short8*)(wk + (size_t)((mt0 + 1) * 32 + l31) * 64 + cc + c0));
            half8 a2 = as_h8(*(const short8*)(wk + (size_t)((mt0 + 2) * 32 + l31) * 64 + cc + c0));
            acc0 = __builtin_amdgcn_mfma_f32_32x32x16_f16(a0, bfrag, acc0, 0, 0, 0);
            acc1 = __builtin_amdgcn_mfma_f32_32x32x16_f16(a1, bfrag, acc1, 0, 0, 0);
            acc2 = __builtin_amdgcn_mfma_f32_32x32x16_f16(a2, bfrag, acc2, 0, 0, 0);
        }
    }

    if (khalf) {
        float* rp = red + mhalf * 3072;
        #pragma unroll
        for (int r = 0; r < 16; r++) {
            rp[(0 * 16 + r) * 64 + lane] = acc0[r];
            rp[(1 * 16 + r) * 64 + lane] = acc1[r];
            rp[(2 * 16 + r) * 64 + lane] = acc2[r];
        }
    }
    __syncthreads();
    if (!khalf) {
        const float* rp = red + mhalf * 3072;
        #pragma unroll
        for (int r = 0; r < 16; r++) {
            acc0[r] += rp[(0 * 16 + r) * 64 + lane];
            acc1[r] += rp[(1 * 16 + r) * 64 + lane];
            acc2[r] += rp[(2 * 16 + r) * 64 + lane];
        }
        float* row = off_all + ((size_t)b * HW + npos) * OFFROW;
        #pragma unroll
        for (int m = 0; m < 3; m++) {
            const f32x16& a = (m == 0) ? acc0 : (m == 1) ? acc1 : acc2;
            int mt = mt0 + m;
            #pragma unroll
            for (int q = 0; q < 4; q++) {
                int base = mt * 32 + 8 * q + 4 * lh;
                if (base < 166) {
                    float4 vv = make_float4(a[4 * q + 0] + bias_all[base + 0],
                                            a[4 * q + 1] + bias_all[base + 1],
                                            a[4 * q + 2] + bias_all[base + 2],
                                            a[4 * q + 3] + bias_all[base + 3]);
                    *(float4*)(row + base) = vv;
                }
            }
        }
    }
}

// store + accumulate per-position (sum, max) stats (bias included)
__device__ __forceinline__ void store_tile_stats(int b, int tile, int lane, int g,
                                                 const float* __restrict__ bias,
                                                 const f32x16& acc0, const f32x16& acc1,
                                                 float* __restrict__ res,
                                                 float& psum, float& pmax)
{
    const int l31 = lane & 31, lh = lane >> 5;
    const int npos = tile * 32 + l31;
    size_t rb = (((size_t)b * 3 + g) * 64) * HW + npos;
    #pragma unroll
    for (int r = 0; r < 16; r++) {
        int co = (r & 3) + 8 * (r >> 2) + 4 * lh;
        float v0 = acc0[r] + bias[co];
        float v1 = acc1[r] + bias[co + 32];
        res[rb + (size_t)co * HW]        = v0;
        res[rb + (size_t)(co + 32) * HW] = v1;
        psum += v0 + v1;
        pmax = fmaxf(pmax, fmaxf(v0, v1));
    }
}

// patch geometry (K7-sized, shared by all three convs) -- R6 proven config
#define MG  5
#define PNY 12
#define PNX 43
#define PXS 144             // px stride bytes (128B data + 16B pad)
#define PRS (PNX * PXS)

// ---------------- one tap span from the staged LDS patch --------------------
// R6/R11/R13 proven form: rolling offset prefetch only; no setprio.
template<int K, int PAD>
__device__ __forceinline__ void deform_span(
    const float* __restrict__ offp, const ushort_t* __restrict__ wtf,
    int kk0, int kk1, int h, int w, int w0, int l31, int lh,
    const char* lds, f32x16& acc0, f32x16& acc1)
{
    const int lh16 = lh * 16;
    const float2* offp2 = (const float2*)offp;
    float2 off = offp2[kk0];
    for (int kk = kk0; kk < kk1; kk++) {
        float2 noff = offp2[(kk + 1 < kk1) ? kk + 1 : kk];

        int ky = kk / K, kx = kk % K;
        float ys = (float)(h + ky - PAD) + off.x;
        float xs = (float)(w + kx - PAD) + off.y;
        float y0f = floorf(ys), x0f = floorf(xs);
        float fy = ys - y0f, fx = xs - x0f;
        int iy0 = (int)y0f, ix0 = (int)x0f;
        int iy1 = iy0 + 1, ix1 = ix0 + 1;
        float oky0 = ((unsigned)iy0 < (unsigned)H) ? 1.f : 0.f;
        float oky1 = ((unsigned)iy1 < (unsigned)H) ? 1.f : 0.f;
        float okx0 = ((unsigned)ix0 < (unsigned)W) ? 1.f : 0.f;
        float okx1 = ((unsigned)ix1 < (unsigned)W) ? 1.f : 0.f;
        float w00 = (1.f - fy) * (1.f - fx) * oky0 * okx0;
        float w01 = (1.f - fy) * fx * oky0 * okx1;
        float w10 = fy * (1.f - fx) * oky1 * okx0;
        float w11 = fy * fx * oky1 * okx1;
        int cy0 = min(max(iy0, 0), H - 1), cy1 = min(max(iy1, 0), H - 1);
        int cx0 = min(max(ix0, 0), W - 1), cx1 = min(max(ix1, 0), W - 1);
        int r0 = min(max(cy0 - h + MG, 0), PNY - 1);
        int r1 = min(max(cy1 - h + MG, 0), PNY - 1);
        int p0 = min(max(cx0 - w0 + MG, 0), PNX - 1);
        int p1 = min(max(cx1 - w0 + MG, 0), PNX - 1);
        const char* b00 = lds + r0 * PRS + p0 * PXS + lh16;
        const char* b01 = lds + r0 * PRS + p1 * PXS + lh16;
        const char* b10 = lds + r1 * PRS + p0 * PXS + lh16;
        const char* b11 = lds + r1 * PRS + p1 * PXS + lh16;

        half8 W00 = splat8(w00), W01 = splat8(w01);
        half8 W10 = splat8(w10), W11 = splat8(w11);
        const ushort_t* wkf = wtf + (size_t)kk * 4096;
        #pragma unroll
        for (int cs = 0; cs < 4; cs++) {
            half8 q00 = *(const half8*)(b00 + cs * 32);
            half8 q01 = *(const half8*)(b01 + cs * 32);
            half8 q10 = *(const half8*)(b10 + cs * 32);
            half8 q11 = *(const half8*)(b11 + cs * 32);
            half8 bfrag = q00 * W00 + q01 * W01 + q10 * W10 + q11 * W11;
            half8 a0 = as_h8(*(const short8*)(wkf + (size_t)(((0 * 4 + cs) * 2 + lh) * 32 + l31) * 8));
            half8 a1 = as_h8(*(const short8*)(wkf + (size_t)(((1 * 4 + cs) * 2 + lh) * 32 + l31) * 8));
            acc0 = __builtin_amdgcn_mfma_f32_32x32x16_f16(a0, bfrag, acc0, 0, 0, 0);
            acc1 = __builtin_amdgcn_mfma_f32_32x32x16_f16(a1, bfrag, acc1, 0, 0, 0);
        }
        off = noff;
    }
}

// ---------------- fully-fused deformable conv: 1 block = 1 tile, all 3 convs
// + fused spatial mean/max (spin) epilogue (R17 proven config).
__global__ __launch_bounds__(256, 2) void deform_fused_kernel(
    const ushort_t* __restrict__ xb, const float* __restrict__ off_all,
    const ushort_t* __restrict__ wt3, const ushort_t* __restrict__ wt5,
    const ushort_t* __restrict__ wt7,
    const float* __restrict__ b3, const float* __restrict__ b5,
    const float* __restrict__ b7,
    float* __restrict__ res, float* __restrict__ spin)
{
    __shared__ __align__(16) char lds[PNY * PNX * PXS];   // 74304B
    const int t = threadIdx.x;
    const int wave = t >> 6, lane = t & 63;
    const int xcd = blockIdx.x & 7, u = blockIdx.x >> 3;
    const int b = xcd >> 1;
    const int tile = u * 2 + (xcd & 1);     // [0,288)

    const int l31 = lane & 31, lh = lane >> 5;
    const int h  = tile / 3;
    const int w0 = (tile % 3) * 32;
    const int w  = w0 + l31;
    const int npos = h * 96 + w;

    // ---- cooperative staging: PNY x PNX px, 8 x 16B chunks each ----
    const ushort_t* xsrc = xb + (size_t)b * HWP * 64;
    constexpr int NCH = PNY * PNX * 8;
    constexpr int NITER = (NCH + 255) / 256;
    #pragma unroll
    for (int it = 0; it < NITER; it++) {
        int c = t + it * 256;
        if (c < NCH) {
            int rr  = c / (PNX * 8);
            int rem = c - rr * (PNX * 8);
            int pp  = rem >> 3, sub = rem & 7;
            int cy = min(max(h - MG + rr, 0), H - 1);
            int cx = min(max(w0 - MG + pp, 0), W - 1);
            *(float4*)(lds + rr * PRS + pp * PXS + sub * 16) =
                *(const float4*)(xsrc + ((size_t)(cy * W + cx)) * 64 + sub * 8);
        }
    }
    __syncthreads();

    const float* offrow = off_all + ((size_t)b * HW + npos) * OFFROW;

    f32x16 a0A, a1A, a0B, a1B;
    #pragma unroll
    for (int r = 0; r < 16; r++) { a0A[r] = 0.f; a1A[r] = 0.f; a0B[r] = 0.f; a1B[r] = 0.f; }

    if (wave == 0) {
        deform_span<3, 1>(offrow + 0,  wt3, 0, 9,  h, w, w0, l31, lh, lds, a0A, a1A);
        deform_span<5, 2>(offrow + 18, wt5, 0, 12, h, w, w0, l31, lh, lds, a0B, a1B);
    } else if (wave == 1) {
        deform_span<5, 2>(offrow + 18, wt5, 12, 25, h, w, w0, l31, lh, lds, a0A, a1A);
        deform_span<7, 3>(offrow + 68, wt7, 0, 8,   h, w, w0, l31, lh, lds, a0B, a1B);
    } else if (wave == 2) {
        deform_span<7, 3>(offrow + 68, wt7, 8, 29,  h, w, w0, l31, lh, lds, a0A, a1A);
    } else {
        deform_span<7, 3>(offrow + 68, wt7, 29, 49, h, w, w0, l31, lh, lds, a0A, a1A);
    }

    // ---- cross-wave reduce in the (dead) patch area ----
    __syncthreads();
    float* slots = (float*)lds;
    if (wave == 1) {
        float* s0 = slots;            // w1.A  (K5 partial)
        float* s1 = slots + 2048;     // w1.B  (K7 partial)
        #pragma unroll
        for (int r = 0; r < 16; r++) {
            s0[r * 64 + lane]        = a0A[r];
            s0[(16 + r) * 64 + lane] = a1A[r];
            s1[r * 64 + lane]        = a0B[r];
            s1[(16 + r) * 64 + lane] = a1B[r];
        }
    } else if (wave == 3) {
        float* s2 = slots + 4096;     // w3.A  (K7 partial)
        #pragma unroll
        for (int r = 0; r < 16; r++) {
            s2[r * 64 + lane]        = a0A[r];
            s2[(16 + r) * 64 + lane] = a1A[r];
        }
    }
    __syncthreads();
    float psum = 0.f, pmax = -3.402823466e+38f;
    if (wave == 0) {
        store_tile_stats(b, tile, lane, 0, b3, a0A, a1A, res, psum, pmax);
        const float* s0 = slots;
        #pragma unroll
        for (int r = 0; r < 16; r++) {
            a0B[r] += s0[r * 64 + lane];
            a1B[r] += s0[(16 + r) * 64 + lane];
        }
        store_tile_stats(b, tile, lane, 1, b5, a0B, a1B, res, psum, pmax);
    } else if (wave == 2) {
        const float* s1 = slots + 2048;
        const float* s2 = slots + 4096;
        #pragma unroll
        for (int r = 0; r < 16; r++) {
            a0A[r] += s1[r * 64 + lane] + s2[r * 64 + lane];
            a1A[r] += s1[(16 + r) * 64 + lane] + s2[(16 + r) * 64 + lane];
        }
        store_tile_stats(b, tile, lane, 2, b7, a0A, a1A, res, psum, pmax);
    }
    // combine lh halves; stage per-position partials in dead LDS (byte 32768+)
    if (wave == 0 || wave == 2) {
        psum += __shfl_xor(psum, 32);
        pmax = fmaxf(pmax, __shfl_xor(pmax, 32));
        if (lane < 32) {
            float* pr = (float*)lds + 8192 + (wave == 2 ? 64 : 0);
            pr[lane * 2]     = psum;
            pr[lane * 2 + 1] = pmax;
        }
    }
    __syncthreads();
    if (wave == 1 && lane < 32) {
        const float* pr = (const float*)lds + 8192;
        float s = pr[lane * 2]     + pr[64 + lane * 2];
        float m = fmaxf(pr[lane * 2 + 1], pr[64 + lane * 2 + 1]);
        int np = tile * 32 + lane;
        spin[(size_t)b * 2 * HW + np]      = s * (1.f / 192.f);
        spin[(size_t)b * 2 * HW + HW + np] = m;
    }
}

// ---------------- global avg/max pool per (b, ch) ---------------------------
__global__ __launch_bounds__(256) void pool_kernel(const float* __restrict__ res,
                                                   float* __restrict__ avg,
                                                   float* __restrict__ mx) {
    int bc = blockIdx.x;   // NB*192
    const float* r = res + (size_t)bc * HW;
    int t = threadIdx.x;
    float s = 0.f, m = -3.402823466e+38f;
    for (int i = t; i < HW; i += 256) {
        float v = r[i];
        s += v;
        m = fmaxf(m, v);
    }
    #pragma unroll
    for (int off = 32; off > 0; off >>= 1) {
        s += __shfl_down(s, off);
        m = fmaxf(m, __shfl_down(m, off));
    }
    __shared__ float ss[4], sm[4];
    int wid = t >> 6;
    if ((t & 63) == 0) { ss[wid] = s; sm[wid] = m; }
    __syncthreads();
    if (t == 0) {
        s = ss[0] + ss[1] + ss[2] + ss[3];
        m = fmaxf(fmaxf(sm[0], sm[1]), fmaxf(sm[2], sm[3]));
        avg[bc] = s * (1.f / (float)HW);
        mx[bc]  = m;
    }
}

// ---------------- attention maps: 7x7 spatial conv AND channel MLP ----------
__global__ __launch_bounds__(256) void att_kernel(
    const float* __restrict__ spin, const float* __restrict__ w_sp,
    float* __restrict__ sp,
    const float* __restrict__ avg, const float* __restrict__ mx,
    const float* __restrict__ w1, const float* __restrict__ w2,
    float* __restrict__ ch)
{
    const int bid = blockIdx.x;
    const int t = threadIdx.x;
    if (bid < 576) {
        int gt  = bid * 256 + t;
        int idx = gt >> 2;
        int q   = gt & 3;
        int w = idx % W;
        int h = (idx / W) % H;
        int b = idx / HW;
        int ci  = q >> 1;
        int dy0 = (q & 1) ? 4 : 0;
        int dy1 = (q & 1) ? 7 : 4;
        const float* pin = spin + ((size_t)b * 2 + ci) * HW;
        const float* wp  = w_sp + ci * 49;
        float acc = 0.f;
        for (int dy = dy0; dy < dy1; dy++) {
            int yy = h + dy - 3;
            if (yy < 0 || yy >= H) continue;
            #pragma unroll
            for (int dx = 0; dx < 7; dx++) {
                int xx = w + dx - 3;
                if (xx < 0 || xx >= W) continue;
                acc = fmaf(pin[yy * W + xx], wp[dy * 7 + dx], acc);
            }
        }
        acc += __shfl_xor(acc, 1);
        acc += __shfl_xor(acc, 2);
        if (q == 0) sp[idx] = 1.f / (1.f + expf(-acc));
        return;
    }
    int b = bid - 576;
    __shared__ float sa[192], sm_[192], h1a[12], h1m[12];
    if (t < 192) { sa[t] = avg[b * 192 + t]; sm_[t] = mx[b * 192 + t]; }
    __syncthreads();
    if (t < 192) {
        int j = t >> 4, lg = t & 15;
        float s1 = 0.f, s2 = 0.f;
        #pragma unroll
        for (int i = 0; i < 12; i++) {
            int c = lg + i * 16;
            float wv = w1[j * 192 + c];
            s1 = fmaf(wv, sa[c], s1);
            s2 = fmaf(wv, sm_[c], s2);
        }
        #pragma unroll
        for (int d = 1; d < 16; d <<= 1) {
            s1 += __shfl_xor(s1, d);
            s2 += __shfl_xor(s2, d);
        }
        if (lg == 0) {
            h1a[j] = fmaxf(s1, 0.f);
            h1m[j] = fmaxf(s2, 0.f);
        }
    }
    __syncthreads();
    if (t < 192) {
        float s = 0.f;
        #pragma unroll
        for (int j = 0; j < 12; j++)
            s = fmaf(w2[t * 12 + j], h1a[j] + h1m[j], s);
        ch[b * 192 + t] = 1.f / (1.f + expf(-s));
    }
}

// ---------------- final combine (float4, 4 hw per thread) -------------------
__global__ void final_kernel(const float* __restrict__ res,
                             const float* __restrict__ sp,
                             const float* __restrict__ ch,
                             float* __restrict__ out) {
    int idx = blockIdx.x * 256 + threadIdx.x;   // NB*64*(HW/4)
    int hw4 = idx % (HW / 4);
    int co  = (idx / (HW / 4)) % 64;
    int b   = idx / (64 * (HW / 4));
    size_t rb = (size_t)b * 192 * HW + (size_t)co * HW + hw4 * 4;
    float4 a1 = *(const float4*)(res + rb);
    float4 a2 = *(const float4*)(res + rb + (size_t)64 * HW);
    float4 a3 = *(const float4*)(res + rb + (size_t)128 * HW);
    float4 spv = *(const float4*)(sp + (size_t)b * HW + hw4 * 4);
    float c1 = ch[b * 192 + co];
    float c2 = ch[b * 192 + 64 + co];
    float c3 = ch[b * 192 + 128 + co];
    float4 o;
    o.x = a1.x * (spv.x + c1) + a2.x * (spv.x + c2) + a3.x * (spv.x + c3);
    o.y = a1.y * (spv.y + c1) + a2.y * (spv.y + c2) + a3.y * (spv.y + c3);
    o.z = a1.z * (spv.z + c1) + a2.z * (spv.z + c2) + a3.z * (spv.z + c3);
    o.w = a1.w * (spv.w + c1) + a2.w * (spv.w + c2) + a3.w * (spv.w + c3);
    *(float4*)(out + ((size_t)b * 64 + co) * HW + hw4 * 4) = o;
}

extern "C" void kernel_launch(void* const* d_in, const int* in_sizes, int n_in,
                              void* d_out, int out_size, void* d_ws, size_t ws_size,
                              hipStream_t stream) {
    const float* x      = (const float*)d_in[0];
    const float* w_off3 = (const float*)d_in[1];
    const float* b_off3 = (const float*)d_in[2];
    const float* w_off5 = (const float*)d_in[3];
    const float* b_off5 = (const float*)d_in[4];
    const float* w_off7 = (const float*)d_in[5];
    const float* b_off7 = (const float*)d_in[6];
    const float* w_d3   = (const float*)d_in[7];
    const float* b_d3   = (const float*)d_in[8];
    const float* w_d5   = (const float*)d_in[9];
    const float* b_d5   = (const float*)d_in[10];
    const float* w_d7   = (const float*)d_in[11];
    const float* b_d7   = (const float*)d_in[12];
    const float* w_sp   = (const float*)d_in[13];
    const float* w_ca1  = (const float*)d_in[14];
    const float* w_ca2  = (const float*)d_in[15];

    float* ws = (float*)d_ws;
    float* off_all = ws + OFF_ALL;
    float* res     = ws + RES;
    ushort_t* xb16 = (ushort_t*)(ws + XB16);
    ushort_t* wt3  = (ushort_t*)(ws + WTD3);
    ushort_t* wt5  = (ushort_t*)(ws + WTD5);
    ushort_t* wt7  = (ushort_t*)(ws + WTD7);
    ushort_t* woff = (ushort_t*)(ws + WOFF);
    float* boff = ws + BOFF;
    float* spin = ws + SPIN;
    float* sp   = ws + SPATT;
    float* avgp = ws + POOLAVG;
    float* mxp  = ws + POOLMAX;
    float* chp  = ws + CHATT;

    prep_kernel<<<2336, 256, 0, stream>>>(x, xb16, w_d3, w_d5, w_d7,
                                          b_off3, b_off5, b_off7,
                                          w_off3, w_off5, w_off7,
                                          wt3, wt5, wt7, woff, boff);

    offset_mfma_kernel<<<1152, 256, 0, stream>>>(xb16, woff, boff, off_all);

    deform_fused_kernel<<<1152, 256, 0, stream>>>(xb16, off_all, wt3, wt5, wt7,
                                                  b_d3, b_d5, b_d7, res, spin);

    pool_kernel<<<768, 256, 0, stream>>>(res, avgp, mxp);
    att_kernel<<<580, 256, 0, stream>>>(spin, w_sp, sp, avgp, mxp,
                                        w_ca1, w_ca2, chp);

    final_kernel<<<2304, 256, 0, stream>>>(res, sp, chp, (float*)d_out);
}